// Round 7
// baseline (430.006 us; speedup 1.0000x reference)
//
#include <hip/hip_runtime.h>

typedef unsigned short u16;
typedef __bf16 bf16x8 __attribute__((ext_vector_type(8)));
typedef float f32x4 __attribute__((ext_vector_type(4)));

#define D_MODEL 1024
#define NH 16
#define DH 64
#define BB 2
#define SS 2048

__device__ __forceinline__ u16 f2bf_fast(float f) {
    union { float f; unsigned int u; } v; v.f = f;
    return (u16)((v.u + 0x8000u) >> 16);
}
// pack 8 fp32 -> 8 bf16 (half-up): 8 add + 4 perm
__device__ __forceinline__ uint4 pack8(const float4& a, const float4& b) {
    unsigned int a0 = __float_as_uint(a.x) + 0x8000u, a1 = __float_as_uint(a.y) + 0x8000u;
    unsigned int a2 = __float_as_uint(a.z) + 0x8000u, a3 = __float_as_uint(a.w) + 0x8000u;
    unsigned int b0 = __float_as_uint(b.x) + 0x8000u, b1 = __float_as_uint(b.y) + 0x8000u;
    unsigned int b2 = __float_as_uint(b.z) + 0x8000u, b3 = __float_as_uint(b.w) + 0x8000u;
    uint4 r;
    r.x = __builtin_amdgcn_perm(a1, a0, 0x07060302);
    r.y = __builtin_amdgcn_perm(a3, a2, 0x07060302);
    r.z = __builtin_amdgcn_perm(b1, b0, 0x07060302);
    r.w = __builtin_amdgcn_perm(b3, b2, 0x07060302);
    return r;
}

// Wq,Wk,Wv,Wo fp32 -> cW bf16
__global__ __launch_bounds__(256) void cvtw_kernel(
    const float* __restrict__ Wq, const float* __restrict__ Wk,
    const float* __restrict__ Wv, const float* __restrict__ Wo, u16* __restrict__ cW)
{
    int z = blockIdx.y;
    const float* src = (z == 0) ? Wq : (z == 1) ? Wk : (z == 2) ? Wv : Wo;
    u16* dst = cW + (size_t)z * D_MODEL * D_MODEL;
    size_t base = ((size_t)blockIdx.x * 256 + threadIdx.x) * 8;
    float4 a = *reinterpret_cast<const float4*>(src + base);
    float4 b = *reinterpret_cast<const float4*>(src + base + 4);
    *reinterpret_cast<uint4*>(dst + base) = pack8(a, b);
}

// mask[B,S,S] int32 -> bitmask pm[B*S][S/64] u64. 4096 waves, 32 words each.
__global__ __launch_bounds__(256) void maskpack_kernel(
    const int* __restrict__ mask, unsigned long long* __restrict__ pm)
{
    int gw = (blockIdx.x * 256 + threadIdx.x) >> 6;   // 0..4095
    int l = threadIdx.x & 63;
#pragma unroll 4
    for (int i = 0; i < 32; ++i) {
        int widx = gw * 32 + i;
        int m = mask[(size_t)widx * 64 + l];
        unsigned long long bits = __ballot(m != 0);
        if (l == 0) pm[widx] = bits;
    }
}

// NT GEMM: C[m,n] = (sum_k A[m,k]*W[n,k] + bias[n]) * oscale.  M=4096, N=K=1024.
// All LDS stride 72 (conflict-free b128 fragment reads); staged via registers,
// software-pipelined (kt+1 loads issued after barrier B).
// VOUT: write C transposed per-head -> vhT[b][h][d][s] via LDS re-layout.
template<int AF32, int OF32, int QKV, int VOUT>
__device__ void gemm128(const void* Avp, const u16* __restrict__ Wb,
                        const float* __restrict__ bias, void* outp, float oscale)
{
    __shared__ __align__(16) u16 smem[128 * 144];
    u16* lA = smem;                 // 128 x 72
    u16* lW = smem + 128 * 72;      // 128 x 72
    const int t = threadIdx.x, w = t >> 6, l = t & 63;
    const int blockM = blockIdx.x * 128, blockN = blockIdx.y * 128;
    const int lrow = l >> 3, lcol = (l & 7) * 8;
    const int quad = l >> 4, c16 = l & 15;

    f32x4 acc[4][4] = {};
    float4 rx0[4], rx1[4];
    uint4 ra[4], rw[4];

    // prime kt=0
#pragma unroll
    for (int i = 0; i < 4; ++i) {
        int row = (w * 4 + i) * 8 + lrow;
        if (AF32) {
            const float* Af = (const float*)Avp;
            size_t off = (size_t)(blockM + row) * 1024 + lcol;
            rx0[i] = *reinterpret_cast<const float4*>(Af + off);
            rx1[i] = *reinterpret_cast<const float4*>(Af + off + 4);
        } else {
            ra[i] = *reinterpret_cast<const uint4*>(
                (const u16*)Avp + (size_t)(blockM + row) * 1024 + lcol);
        }
        rw[i] = *reinterpret_cast<const uint4*>(
            Wb + (size_t)(blockN + row) * 1024 + lcol);
    }

    for (int kt = 0; kt < 16; ++kt) {
        __syncthreads();  // A: prev compute's LDS reads done
#pragma unroll
        for (int i = 0; i < 4; ++i) {
            int row = (w * 4 + i) * 8 + lrow;
            *reinterpret_cast<uint4*>(&lA[row * 72 + lcol]) =
                AF32 ? pack8(rx0[i], rx1[i]) : ra[i];
            *reinterpret_cast<uint4*>(&lW[row * 72 + lcol]) = rw[i];
        }
        __syncthreads();  // B: stores visible
        {
            int ktn = (kt < 15) ? kt + 1 : kt;
#pragma unroll
            for (int i = 0; i < 4; ++i) {
                int row = (w * 4 + i) * 8 + lrow;
                if (AF32) {
                    const float* Af = (const float*)Avp;
                    size_t off = (size_t)(blockM + row) * 1024 + ktn * 64 + lcol;
                    rx0[i] = *reinterpret_cast<const float4*>(Af + off);
                    rx1[i] = *reinterpret_cast<const float4*>(Af + off + 4);
                } else {
                    ra[i] = *reinterpret_cast<const uint4*>(
                        (const u16*)Avp + (size_t)(blockM + row) * 1024 + ktn * 64 + lcol);
                }
                rw[i] = *reinterpret_cast<const uint4*>(
                    Wb + (size_t)(blockN + row) * 1024 + ktn * 64 + lcol);
            }
        }
#pragma unroll
        for (int ks = 0; ks < 2; ++ks) {
            bf16x8 af[4], bfr[4];
#pragma unroll
            for (int mi = 0; mi < 4; ++mi)
                af[mi] = *reinterpret_cast<const bf16x8*>(
                    &lA[((w & 1) * 64 + mi * 16 + c16) * 72 + ks * 32 + quad * 8]);
#pragma unroll
            for (int ni = 0; ni < 4; ++ni)
                bfr[ni] = *reinterpret_cast<const bf16x8*>(
                    &lW[((w >> 1) * 64 + ni * 16 + c16) * 72 + ks * 32 + quad * 8]);
#pragma unroll
            for (int mi = 0; mi < 4; ++mi)
#pragma unroll
                for (int ni = 0; ni < 4; ++ni)
                    acc[mi][ni] = __builtin_amdgcn_mfma_f32_16x16x32_bf16(
                        af[mi], bfr[ni], acc[mi][ni], 0, 0, 0);
        }
    }

    if (VOUT) {
        // V projection: write C^T per head -> vhT[b][h][d][s] (coalesced in s)
        __syncthreads();
        const int n_base = (w >> 1) * 64, m_base = (w & 1) * 64;
#pragma unroll
        for (int ni = 0; ni < 4; ++ni) {
            int n_local = n_base + ni * 16 + c16;
            float bv = bias[blockN + n_local];
#pragma unroll
            for (int mi = 0; mi < 4; ++mi) {
#pragma unroll
                for (int r2 = 0; r2 < 4; r2 += 2) {
                    unsigned int lo = (unsigned int)f2bf_fast(acc[mi][ni][r2] + bv);
                    unsigned int hi = (unsigned int)f2bf_fast(acc[mi][ni][r2 + 1] + bv);
                    *reinterpret_cast<unsigned int*>(
                        &smem[n_local * 144 + m_base + mi * 16 + quad * 4 + r2]) =
                        lo | (hi << 16);
                }
            }
        }
        __syncthreads();
        const int bb = blockM >> 11, s0 = blockM & 2047;
#pragma unroll
        for (int i = 0; i < 8; ++i) {
            int idx = t + i * 256;
            int row = idx >> 4, ch = idx & 15;
            uint4 val = *reinterpret_cast<const uint4*>(&smem[row * 144 + ch * 8]);
            int hh = (blockN + row) >> 6, d = (blockN + row) & 63;
            *reinterpret_cast<uint4*>(
                (u16*)outp + (((size_t)(bb * NH + hh)) * DH + d) * SS + s0 + ch * 8) = val;
        }
        return;
    }

    const int m0 = blockM + (w & 1) * 64, n0 = blockN + (w >> 1) * 64;
#pragma unroll
    for (int ni = 0; ni < 4; ++ni) {
        int n = n0 + ni * 16 + c16;
        float bv = bias[n];
#pragma unroll
        for (int mi = 0; mi < 4; ++mi) {
#pragma unroll
            for (int r = 0; r < 4; ++r) {
                int m = m0 + mi * 16 + quad * 4 + r;
                float val = (acc[mi][ni][r] + bv) * oscale;
                size_t idx;
                if (QKV) {
                    int bb = m >> 11, s = m & 2047, hh = n >> 6, d = n & 63;
                    idx = (((size_t)(bb * NH + hh)) * SS + s) * DH + d;
                } else {
                    idx = (size_t)m * 1024 + n;
                }
                if (OF32) ((float*)outp)[idx] = val;
                else      ((u16*)outp)[idx] = f2bf_fast(val);
            }
        }
    }
}

__global__ __launch_bounds__(256) void qkv_kernel(
    const float* __restrict__ q, const float* __restrict__ k, const float* __restrict__ v,
    const u16* __restrict__ cW,
    const float* __restrict__ bq, const float* __restrict__ bk, const float* __restrict__ bv,
    u16* __restrict__ qh, u16* __restrict__ kh, u16* __restrict__ vhT)
{
    int z = blockIdx.z;
    const float* A = (z == 0) ? q : (z == 1) ? k : v;
    const u16* W = cW + (size_t)z * D_MODEL * D_MODEL;
    const float* bias = (z == 0) ? bq : (z == 1) ? bk : bv;
    if (z == 2) {
        gemm128<1, 0, 1, 1>(A, W, bias, vhT, 1.0f);
    } else {
        u16* out = (z == 0) ? qh : kh;
        float oscale = (z == 0) ? 0.125f : 1.0f;  // fold 1/sqrt(dh) into Q
        gemm128<1, 0, 1, 0>(A, W, bias, out, oscale);
    }
}

__global__ __launch_bounds__(256) void oproj_kernel(
    const u16* __restrict__ A, const u16* __restrict__ cWo,
    const float* __restrict__ bo, float* __restrict__ out)
{
    gemm128<0, 1, 0, 0>(A, cWo, bo, out, 1.0f);
}

// Flash attention, S^T scheme. V comes pre-transposed (vhT[b][h][d][s]) so
// both K and V^T staging are identical coalesced b128 load->store chains.
// lQ and lP alias (Q only needed in prologue). LDS = 27.6 KB.
__global__ __launch_bounds__(256) void attn_kernel(
    const u16* __restrict__ qh, const u16* __restrict__ kh, const u16* __restrict__ vhT,
    const unsigned long long* __restrict__ pm, u16* __restrict__ ao)
{
    __shared__ __align__(16) u16 smem[64 * 72 * 3];
    u16* lQP = smem;                // Q staging, then P[q][sk]
    u16* lK  = smem + 64 * 72;      // K tile; O-restage at epilogue
    u16* lVt = smem + 2 * 64 * 72;  // V^T[d][sk]

    const int t = threadIdx.x, w = t >> 6, l = t & 63;
    const int qt = blockIdx.x, h = blockIdx.y, b = blockIdx.z;
    const int sq0 = qt * 64;
    const size_t headbase = ((size_t)(b * NH + h)) * SS * DH;
    const int quad = l >> 4, c16 = l & 15;
    const int lrow = l >> 3, lcol = (l & 7) * 8;

    // stage Q once (pre-scaled by 0.125)
#pragma unroll
    for (int i = 0; i < 2; ++i) {
        int row = (w * 2 + i) * 8 + lrow;
        uint4 rq = *reinterpret_cast<const uint4*>(
            qh + headbase + (size_t)(sq0 + row) * DH + lcol);
        *reinterpret_cast<uint4*>(&lQP[row * 72 + lcol]) = rq;
    }
    __syncthreads();
    bf16x8 qf[2];
#pragma unroll
    for (int ks = 0; ks < 2; ++ks)
        qf[ks] = *reinterpret_cast<const bf16x8*>(
            &lQP[(w * 16 + c16) * 72 + ks * 32 + quad * 8]);

    f32x4 oAcc[4] = {};
    float rsumAcc = 0.f;
    const size_t pmrow = ((size_t)b * SS + sq0 + w * 16 + c16) * 32;

    // prime kt=0
    uint4 rk[2], rv[2];
    unsigned long long mw_cur, mw_next;
#pragma unroll
    for (int i = 0; i < 2; ++i) {
        int row = (w * 2 + i) * 8 + lrow;
        rk[i] = *reinterpret_cast<const uint4*>(kh + headbase + (size_t)row * DH + lcol);
        rv[i] = *reinterpret_cast<const uint4*>(vhT + headbase + (size_t)row * SS + lcol);
    }
    mw_cur = pm[pmrow];

    for (int kt = 0; kt < 32; ++kt) {
        __syncthreads();  // A: prev compute's LDS reads done
#pragma unroll
        for (int i = 0; i < 2; ++i) {
            int row = (w * 2 + i) * 8 + lrow;
            *reinterpret_cast<uint4*>(&lK[row * 72 + lcol]) = rk[i];
            *reinterpret_cast<uint4*>(&lVt[row * 72 + lcol]) = rv[i];
        }
        __syncthreads();  // B
        {
            int ktn = (kt < 31) ? kt + 1 : kt;
            const int sk0n = ktn * 64;
#pragma unroll
            for (int i = 0; i < 2; ++i) {
                int row = (w * 2 + i) * 8 + lrow;
                rk[i] = *reinterpret_cast<const uint4*>(
                    kh + headbase + (size_t)(sk0n + row) * DH + lcol);
                rv[i] = *reinterpret_cast<const uint4*>(
                    vhT + headbase + (size_t)row * SS + sk0n + lcol);
            }
            mw_next = pm[pmrow + ktn];
        }

        // S^T = K Q^T : lane holds S^T[sk=ni*16+quad*4+r][q=w*16+c16]
        f32x4 sAcc[4] = {};
#pragma unroll
        for (int ks = 0; ks < 2; ++ks) {
#pragma unroll
            for (int ni = 0; ni < 4; ++ni) {
                bf16x8 kf = *reinterpret_cast<const bf16x8*>(
                    &lK[(ni * 16 + c16) * 72 + ks * 32 + quad * 8]);
                sAcc[ni] = __builtin_amdgcn_mfma_f32_16x16x32_bf16(
                    kf, qf[ks], sAcc[ni], 0, 0, 0);
            }
        }

        // mask + exp + packed b64 P stores
        unsigned long long mq = mw_cur >> (quad * 4);
        unsigned int mlo = (unsigned int)mq, mhi = (unsigned int)(mq >> 32);
#pragma unroll
        for (int ni = 0; ni < 4; ++ni) {
            unsigned int half = (ni < 2) ? mlo : mhi;
            unsigned int sh = (ni & 1) * 16;
            float p0 = ((half >> (sh + 0)) & 1u) ? __expf(sAcc[ni][0]) : 0.f;
            float p1 = ((half >> (sh + 1)) & 1u) ? __expf(sAcc[ni][1]) : 0.f;
            float p2 = ((half >> (sh + 2)) & 1u) ? __expf(sAcc[ni][2]) : 0.f;
            float p3 = ((half >> (sh + 3)) & 1u) ? __expf(sAcc[ni][3]) : 0.f;
            rsumAcc += (p0 + p1) + (p2 + p3);
            uint2 pv;
            pv.x = __builtin_amdgcn_perm(__float_as_uint(p1) + 0x8000u,
                                         __float_as_uint(p0) + 0x8000u, 0x07060302);
            pv.y = __builtin_amdgcn_perm(__float_as_uint(p3) + 0x8000u,
                                         __float_as_uint(p2) + 0x8000u, 0x07060302);
            *reinterpret_cast<uint2*>(
                &lQP[(w * 16 + c16) * 72 + ni * 16 + quad * 4]) = pv;
        }
        mw_cur = mw_next;
        // wave-private lP RAW: drain DS queue (no cross-wave barrier needed)
        __asm__ volatile("s_waitcnt lgkmcnt(0)" ::: "memory");

        // O += P @ V
#pragma unroll
        for (int ks = 0; ks < 2; ++ks) {
            bf16x8 pf = *reinterpret_cast<const bf16x8*>(
                &lQP[(w * 16 + c16) * 72 + ks * 32 + quad * 8]);
#pragma unroll
            for (int no = 0; no < 4; ++no) {
                bf16x8 vf = *reinterpret_cast<const bf16x8*>(
                    &lVt[(no * 16 + c16) * 72 + ks * 32 + quad * 8]);
                oAcc[no] = __builtin_amdgcn_mfma_f32_16x16x32_bf16(
                    pf, vf, oAcc[no], 0, 0, 0);
            }
        }
    }

    // epilogue: reduce row sums, normalize, restage O in lK, coalesced store
    __syncthreads();
    float s = rsumAcc;
    s += __shfl_xor(s, 16);
    s += __shfl_xor(s, 32);
    float rinv = 1.0f / s;
    float linv[4];
#pragma unroll
    for (int r = 0; r < 4; ++r)
        linv[r] = __shfl(rinv, quad * 4 + r);
#pragma unroll
    for (int no = 0; no < 4; ++no)
#pragma unroll
        for (int r = 0; r < 4; ++r)
            lK[(w * 16 + quad * 4 + r) * 72 + no * 16 + c16] =
                f2bf_fast(oAcc[no][r] * linv[r]);
    __syncthreads();
#pragma unroll
    for (int i = 0; i < 2; ++i) {
        int idx = t + i * 256;
        int row = idx >> 3, ch = idx & 7;
        uint4 val = *reinterpret_cast<const uint4*>(&lK[row * 72 + ch * 8]);
        *reinterpret_cast<uint4*>(
            ao + ((size_t)b * SS + sq0 + row) * D_MODEL + h * DH + ch * 8) = val;
    }
}

extern "C" void kernel_launch(void* const* d_in, const int* in_sizes, int n_in,
                              void* d_out, int out_size, void* d_ws, size_t ws_size,
                              hipStream_t stream)
{
    const float* q    = (const float*)d_in[0];
    const float* k    = (const float*)d_in[1];
    const float* v    = (const float*)d_in[2];
    const int*   mask = (const int*)d_in[3];
    const float* Wq   = (const float*)d_in[4];
    const float* bq   = (const float*)d_in[5];
    const float* Wk   = (const float*)d_in[6];
    const float* bk   = (const float*)d_in[7];
    const float* Wv   = (const float*)d_in[8];
    const float* bv   = (const float*)d_in[9];
    const float* Wo   = (const float*)d_in[10];
    const float* bo   = (const float*)d_in[11];

    u16* qh  = (u16*)d_ws;                        // [B][NH][S][DH] bf16 (pre-scaled)
    u16* kh  = qh + (size_t)BB * NH * SS * DH;
    u16* vhT = kh + (size_t)BB * NH * SS * DH;    // [B][NH][DH][S] bf16 (transposed!)
    u16* ao  = vhT + (size_t)BB * NH * SS * DH;   // [B][S][D] bf16
    u16* cW  = ao + (size_t)BB * SS * D_MODEL;    // 4 x 1M bf16
    unsigned long long* pm = (unsigned long long*)(cW + (size_t)4 * D_MODEL * D_MODEL);
    float* out = (float*)d_out;

    cvtw_kernel<<<dim3(512, 4), 256, 0, stream>>>(Wq, Wk, Wv, Wo, cW);
    maskpack_kernel<<<1024, 256, 0, stream>>>(mask, pm);
    qkv_kernel<<<dim3(32, 8, 3), 256, 0, stream>>>(q, k, v, cW, bq, bk, bv, qh, kh, vhT);
    attn_kernel<<<dim3(32, NH, BB), 256, 0, stream>>>(qh, kh, vhT, pm, ao);
    oproj_kernel<<<dim3(32, 8), 256, 0, stream>>>(ao, cW + (size_t)3 * D_MODEL * D_MODEL, bo, out);
}

// Round 8
// 333.309 us; speedup vs baseline: 1.2901x; 1.2901x over previous
//
#include <hip/hip_runtime.h>

typedef unsigned short u16;
typedef __bf16 bf16x8 __attribute__((ext_vector_type(8)));
typedef float f32x4 __attribute__((ext_vector_type(4)));

#define D_MODEL 1024
#define NH 16
#define DH 64
#define BB 2
#define SS 2048

__device__ __forceinline__ u16 f2bf_fast(float f) {
    union { float f; unsigned int u; } v; v.f = f;
    return (u16)((v.u + 0x8000u) >> 16);
}
// pack 8 fp32 -> 8 bf16 (half-up): 8 add + 4 perm
__device__ __forceinline__ uint4 pack8(const float4& a, const float4& b) {
    unsigned int a0 = __float_as_uint(a.x) + 0x8000u, a1 = __float_as_uint(a.y) + 0x8000u;
    unsigned int a2 = __float_as_uint(a.z) + 0x8000u, a3 = __float_as_uint(a.w) + 0x8000u;
    unsigned int b0 = __float_as_uint(b.x) + 0x8000u, b1 = __float_as_uint(b.y) + 0x8000u;
    unsigned int b2 = __float_as_uint(b.z) + 0x8000u, b3 = __float_as_uint(b.w) + 0x8000u;
    uint4 r;
    r.x = __builtin_amdgcn_perm(a1, a0, 0x07060302);
    r.y = __builtin_amdgcn_perm(a3, a2, 0x07060302);
    r.z = __builtin_amdgcn_perm(b1, b0, 0x07060302);
    r.w = __builtin_amdgcn_perm(b3, b2, 0x07060302);
    return r;
}

__device__ __forceinline__ void gld16(const void* g, void* l) {
    __builtin_amdgcn_global_load_lds(
        (const __attribute__((address_space(1))) unsigned int*)g,
        (__attribute__((address_space(3))) unsigned int*)l, 16, 0, 0);
}

// Wq,Wk,Wv,Wo fp32 -> cW bf16
__global__ __launch_bounds__(256) void cvtw_kernel(
    const float* __restrict__ Wq, const float* __restrict__ Wk,
    const float* __restrict__ Wv, const float* __restrict__ Wo, u16* __restrict__ cW)
{
    int z = blockIdx.y;
    const float* src = (z == 0) ? Wq : (z == 1) ? Wk : (z == 2) ? Wv : Wo;
    u16* dst = cW + (size_t)z * D_MODEL * D_MODEL;
    size_t base = ((size_t)blockIdx.x * 256 + threadIdx.x) * 8;
    float4 a = *reinterpret_cast<const float4*>(src + base);
    float4 b = *reinterpret_cast<const float4*>(src + base + 4);
    *reinterpret_cast<uint4*>(dst + base) = pack8(a, b);
}

// q,k,v fp32 -> bf16 (4M elems each)
__global__ __launch_bounds__(256) void cvtin_kernel(
    const float* __restrict__ q, const float* __restrict__ k,
    const float* __restrict__ v, u16* __restrict__ qb)
{
    int z = blockIdx.y;
    const float* src = (z == 0) ? q : (z == 1) ? k : v;
    u16* dst = qb + (size_t)z * BB * SS * D_MODEL;
    size_t base = ((size_t)blockIdx.x * 256 + threadIdx.x) * 8;
    float4 a = *reinterpret_cast<const float4*>(src + base);
    float4 b = *reinterpret_cast<const float4*>(src + base + 4);
    *reinterpret_cast<uint4*>(dst + base) = pack8(a, b);
}

// mask[B,S,S] int32 -> bitmask pm[B*S][S/64] u64
__global__ __launch_bounds__(256) void maskpack_kernel(
    const int* __restrict__ mask, unsigned long long* __restrict__ pm)
{
    int gw = (blockIdx.x * 256 + threadIdx.x) >> 6;   // 0..4095
    int l = threadIdx.x & 63;
#pragma unroll 4
    for (int i = 0; i < 32; ++i) {
        int widx = gw * 32 + i;
        int m = mask[(size_t)widx * 64 + l];
        unsigned long long bits = __ballot(m != 0);
        if (l == 0) pm[widx] = bits;
    }
}

// m97-structure NT GEMM, all-bf16 operands: gld16 width-16 staging, stride-64
// LDS, 2-barrier K-loop. C[m,n] = (sum_k A[m,k]*W[n,k] + bias[n]) * oscale.
// QKV=1: epilogue restages tile in LDS -> coalesced [b,h,s,dh] bf16 writes.
// QKV=0: direct fp32 scatter (64-B chunks).
template<int OF32, int QKV>
__device__ void gemm_bb(const u16* __restrict__ A, const u16* __restrict__ W,
                        const float* __restrict__ bias, void* outp, float oscale)
{
    __shared__ __align__(16) u16 smem[128 * 144];   // staging: 2x 128*64; restage: 128*136
    u16* lA = smem;
    u16* lW = smem + 128 * 64;
    const int t = threadIdx.x, w = t >> 6, l = t & 63;
    const int blockM = blockIdx.x * 128, blockN = blockIdx.y * 128;
    const int lrow = l >> 3, lcol = (l & 7) * 8;
    const int quad = l >> 4, c16 = l & 15;

    f32x4 acc[4][4] = {};

    for (int kt = 0; kt < 16; ++kt) {
        __syncthreads();
#pragma unroll
        for (int i = 0; i < 4; ++i) {
            int c = w * 4 + i;
            int row = c * 8 + lrow;
            gld16(A + (size_t)(blockM + row) * 1024 + kt * 64 + lcol, &lA[c * 512]);
            gld16(W + (size_t)(blockN + row) * 1024 + kt * 64 + lcol, &lW[c * 512]);
        }
        __syncthreads();
#pragma unroll
        for (int ks = 0; ks < 2; ++ks) {
            bf16x8 af[4], bfr[4];
#pragma unroll
            for (int mi = 0; mi < 4; ++mi)
                af[mi] = *reinterpret_cast<const bf16x8*>(
                    &lA[((w & 1) * 64 + mi * 16 + c16) * 64 + ks * 32 + quad * 8]);
#pragma unroll
            for (int ni = 0; ni < 4; ++ni)
                bfr[ni] = *reinterpret_cast<const bf16x8*>(
                    &lW[((w >> 1) * 64 + ni * 16 + c16) * 64 + ks * 32 + quad * 8]);
#pragma unroll
            for (int mi = 0; mi < 4; ++mi)
#pragma unroll
                for (int ni = 0; ni < 4; ++ni)
                    acc[mi][ni] = __builtin_amdgcn_mfma_f32_16x16x32_bf16(
                        af[mi], bfr[ni], acc[mi][ni], 0, 0, 0);
        }
    }

    if (QKV) {
        // restage through LDS (stride 136) -> full-line [b,h,s,dh] writes
        __syncthreads();
        const int m_base = (w & 1) * 64, n_base = (w >> 1) * 64;
#pragma unroll
        for (int ni = 0; ni < 4; ++ni) {
            int n_local = n_base + ni * 16 + c16;
            float bv = bias[blockN + n_local];
#pragma unroll
            for (int mi = 0; mi < 4; ++mi)
#pragma unroll
                for (int r = 0; r < 4; ++r) {
                    int m_local = m_base + mi * 16 + quad * 4 + r;
                    smem[m_local * 136 + n_local] =
                        f2bf_fast((acc[mi][ni][r] + bv) * oscale);
                }
        }
        __syncthreads();
        const int bb = blockM >> 11, s_base = blockM & 2047;
        u16* outb = (u16*)outp;
#pragma unroll
        for (int i = 0; i < 8; ++i) {
            int idx = t + i * 256;
            int mrow = idx >> 4, ch = idx & 15;
            uint4 val = *reinterpret_cast<const uint4*>(&smem[mrow * 136 + ch * 8]);
            int gn = blockN + ch * 8;
            int hh = gn >> 6, dh = gn & 63;
            *reinterpret_cast<uint4*>(
                outb + (((size_t)(bb * NH + hh)) * SS + s_base + mrow) * DH + dh) = val;
        }
        return;
    }

    const int m0 = blockM + (w & 1) * 64, n0 = blockN + (w >> 1) * 64;
#pragma unroll
    for (int ni = 0; ni < 4; ++ni) {
        int n = n0 + ni * 16 + c16;
        float bv = bias[n];
#pragma unroll
        for (int mi = 0; mi < 4; ++mi) {
#pragma unroll
            for (int r = 0; r < 4; ++r) {
                int m = m0 + mi * 16 + quad * 4 + r;
                float val = (acc[mi][ni][r] + bv) * oscale;
                ((float*)outp)[(size_t)m * 1024 + n] = val;
            }
        }
    }
}

__global__ __launch_bounds__(256) void qkv_kernel(
    const u16* __restrict__ qb, const u16* __restrict__ cW,
    const float* __restrict__ bq, const float* __restrict__ bk, const float* __restrict__ bv,
    u16* __restrict__ qh, u16* __restrict__ kh, u16* __restrict__ vh)
{
    int z = blockIdx.z;
    const u16* A = qb + (size_t)z * BB * SS * D_MODEL;
    const u16* W = cW + (size_t)z * D_MODEL * D_MODEL;
    const float* bias = (z == 0) ? bq : (z == 1) ? bk : bv;
    u16* out = (z == 0) ? qh : (z == 1) ? kh : vh;
    float oscale = (z == 0) ? 0.125f : 1.0f;   // fold 1/sqrt(dh) into Q
    gemm_bb<0, 1>(A, W, bias, out, oscale);
}

__global__ __launch_bounds__(256) void oproj_kernel(
    const u16* __restrict__ A, const u16* __restrict__ cWo,
    const float* __restrict__ bo, float* __restrict__ out)
{
    gemm_bb<1, 0>(A, cWo, bo, out, 1.0f);
}

// Flash attention — R6 kernel verbatim (measured 119 us): S^T scheme,
// in-kernel V transpose via v_perm, stride-72 LDS, pipelined staging.
__global__ __launch_bounds__(256) void attn_kernel(
    const u16* __restrict__ qh, const u16* __restrict__ kh, const u16* __restrict__ vh,
    const unsigned long long* __restrict__ pm, u16* __restrict__ ao)
{
    __shared__ __align__(16) u16 lQ[64 * 72];
    __shared__ __align__(16) u16 lK[64 * 72];   // reused as O-tile at epilogue
    __shared__ __align__(16) u16 lVt[64 * 72];  // Vt[d][sk], stride 72
    __shared__ __align__(16) u16 lP[64 * 72];   // P[q][sk], wave-private rows

    const int t = threadIdx.x, w = t >> 6, l = t & 63;
    const int qt = blockIdx.x, h = blockIdx.y, b = blockIdx.z;
    const int sq0 = qt * 64;
    const size_t headbase = ((size_t)(b * NH + h)) * SS * DH;
    const int quad = l >> 4, c16 = l & 15;
    const int lrow = l >> 3, lcol = (l & 7) * 8;
    const int vd2 = t & 31, vg = t >> 5;

    // stage Q once (pre-scaled by 0.125 at projection)
#pragma unroll
    for (int i = 0; i < 2; ++i) {
        int row = (w * 2 + i) * 8 + lrow;
        uint4 rq = *reinterpret_cast<const uint4*>(
            qh + headbase + (size_t)(sq0 + row) * DH + lcol);
        *reinterpret_cast<uint4*>(&lQ[row * 72 + lcol]) = rq;
    }
    __syncthreads();
    bf16x8 qf[2];
#pragma unroll
    for (int ks = 0; ks < 2; ++ks)
        qf[ks] = *reinterpret_cast<const bf16x8*>(
            &lQ[(w * 16 + c16) * 72 + ks * 32 + quad * 8]);

    f32x4 oAcc[4] = {};
    float rsumAcc = 0.f;
    const size_t pmrow = ((size_t)b * SS + sq0 + w * 16 + c16) * 32;

    // prime kt=0 loads
    uint4 rk[2];
    unsigned int rvv[8];
    unsigned long long mw_cur, mw_next;
#pragma unroll
    for (int i = 0; i < 2; ++i) {
        int row = (w * 2 + i) * 8 + lrow;
        rk[i] = *reinterpret_cast<const uint4*>(kh + headbase + (size_t)row * DH + lcol);
    }
#pragma unroll
    for (int e = 0; e < 8; ++e)
        rvv[e] = *reinterpret_cast<const unsigned int*>(
            vh + headbase + (size_t)(vg * 8 + e) * DH + vd2 * 2);
    mw_cur = pm[pmrow + 0];

    for (int kt = 0; kt < 32; ++kt) {
        __syncthreads();  // A: prev compute's LDS reads done
        // ---- store staged tiles ----
#pragma unroll
        for (int i = 0; i < 2; ++i) {
            int row = (w * 2 + i) * 8 + lrow;
            *reinterpret_cast<uint4*>(&lK[row * 72 + lcol]) = rk[i];
        }
        {
            uint4 cA, cB;
            cA.x = __builtin_amdgcn_perm(rvv[1], rvv[0], 0x05040100);
            cA.y = __builtin_amdgcn_perm(rvv[3], rvv[2], 0x05040100);
            cA.z = __builtin_amdgcn_perm(rvv[5], rvv[4], 0x05040100);
            cA.w = __builtin_amdgcn_perm(rvv[7], rvv[6], 0x05040100);
            cB.x = __builtin_amdgcn_perm(rvv[1], rvv[0], 0x07060302);
            cB.y = __builtin_amdgcn_perm(rvv[3], rvv[2], 0x07060302);
            cB.z = __builtin_amdgcn_perm(rvv[5], rvv[4], 0x07060302);
            cB.w = __builtin_amdgcn_perm(rvv[7], rvv[6], 0x07060302);
            *reinterpret_cast<uint4*>(&lVt[(2 * vd2) * 72 + vg * 8]) = cA;
            *reinterpret_cast<uint4*>(&lVt[(2 * vd2 + 1) * 72 + vg * 8]) = cB;
        }
        __syncthreads();  // B
        // ---- issue kt+1 loads (in flight during compute) ----
        {
            int ktn = (kt < 31) ? kt + 1 : kt;
            const int sk0n = ktn * 64;
#pragma unroll
            for (int i = 0; i < 2; ++i) {
                int row = (w * 2 + i) * 8 + lrow;
                rk[i] = *reinterpret_cast<const uint4*>(
                    kh + headbase + (size_t)(sk0n + row) * DH + lcol);
            }
#pragma unroll
            for (int e = 0; e < 8; ++e)
                rvv[e] = *reinterpret_cast<const unsigned int*>(
                    vh + headbase + (size_t)(sk0n + vg * 8 + e) * DH + vd2 * 2);
            mw_next = pm[pmrow + ktn];
        }

        // ---- S^T = K Q^T : lane holds S^T[sk=ni*16+quad*4+r][q=w*16+c16] ----
        f32x4 sAcc[4] = {};
#pragma unroll
        for (int ks = 0; ks < 2; ++ks) {
#pragma unroll
            for (int ni = 0; ni < 4; ++ni) {
                bf16x8 kf = *reinterpret_cast<const bf16x8*>(
                    &lK[(ni * 16 + c16) * 72 + ks * 32 + quad * 8]);
                sAcc[ni] = __builtin_amdgcn_mfma_f32_16x16x32_bf16(
                    kf, qf[ks], sAcc[ni], 0, 0, 0);
            }
        }

        // ---- mask + exp + packed P store (4 x ds_write_b64) ----
        unsigned long long mq = mw_cur >> (quad * 4);
        unsigned int mlo = (unsigned int)mq, mhi = (unsigned int)(mq >> 32);
#pragma unroll
        for (int ni = 0; ni < 4; ++ni) {
            unsigned int half = (ni < 2) ? mlo : mhi;
            unsigned int sh = (ni & 1) * 16;
            unsigned int w0, w1;
            {
                float p0 = ((half >> (sh + 0)) & 1u) ? __expf(sAcc[ni][0]) : 0.f;
                float p1 = ((half >> (sh + 1)) & 1u) ? __expf(sAcc[ni][1]) : 0.f;
                float p2 = ((half >> (sh + 2)) & 1u) ? __expf(sAcc[ni][2]) : 0.f;
                float p3 = ((half >> (sh + 3)) & 1u) ? __expf(sAcc[ni][3]) : 0.f;
                rsumAcc += (p0 + p1) + (p2 + p3);
                w0 = __builtin_amdgcn_perm(__float_as_uint(p1) + 0x8000u,
                                           __float_as_uint(p0) + 0x8000u, 0x07060302);
                w1 = __builtin_amdgcn_perm(__float_as_uint(p3) + 0x8000u,
                                           __float_as_uint(p2) + 0x8000u, 0x07060302);
            }
            uint2 pv; pv.x = w0; pv.y = w1;
            *reinterpret_cast<uint2*>(
                &lP[(w * 16 + c16) * 72 + ni * 16 + quad * 4]) = pv;
        }
        mw_cur = mw_next;
        // wave-private lP RAW: drain DS queue, no cross-wave barrier needed
        __asm__ volatile("s_waitcnt lgkmcnt(0)" ::: "memory");

        // ---- O += P @ V ----
#pragma unroll
        for (int ks = 0; ks < 2; ++ks) {
            bf16x8 pf = *reinterpret_cast<const bf16x8*>(
                &lP[(w * 16 + c16) * 72 + ks * 32 + quad * 8]);
#pragma unroll
            for (int no = 0; no < 4; ++no) {
                bf16x8 vf = *reinterpret_cast<const bf16x8*>(
                    &lVt[(no * 16 + c16) * 72 + ks * 32 + quad * 8]);
                oAcc[no] = __builtin_amdgcn_mfma_f32_16x16x32_bf16(
                    pf, vf, oAcc[no], 0, 0, 0);
            }
        }
    }

    // ---- epilogue ----
    __syncthreads();  // all waves done with lK
    float s = rsumAcc;
    s += __shfl_xor(s, 16);
    s += __shfl_xor(s, 32);
    float rinv = 1.0f / s;
    float linv[4];
#pragma unroll
    for (int r = 0; r < 4; ++r)
        linv[r] = __shfl(rinv, quad * 4 + r);
#pragma unroll
    for (int no = 0; no < 4; ++no)
#pragma unroll
        for (int r = 0; r < 4; ++r)
            lK[(w * 16 + quad * 4 + r) * 72 + no * 16 + c16] =
                f2bf_fast(oAcc[no][r] * linv[r]);
    __syncthreads();
#pragma unroll
    for (int i = 0; i < 2; ++i) {
        int idx = t + i * 256;
        int row = idx >> 3, ch = idx & 7;
        uint4 val = *reinterpret_cast<const uint4*>(&lK[row * 72 + ch * 8]);
        *reinterpret_cast<uint4*>(
            ao + ((size_t)b * SS + sq0 + row) * D_MODEL + h * DH + ch * 8) = val;
    }
}

extern "C" void kernel_launch(void* const* d_in, const int* in_sizes, int n_in,
                              void* d_out, int out_size, void* d_ws, size_t ws_size,
                              hipStream_t stream)
{
    const float* q    = (const float*)d_in[0];
    const float* k    = (const float*)d_in[1];
    const float* v    = (const float*)d_in[2];
    const int*   mask = (const int*)d_in[3];
    const float* Wq   = (const float*)d_in[4];
    const float* bq   = (const float*)d_in[5];
    const float* Wk   = (const float*)d_in[6];
    const float* bk   = (const float*)d_in[7];
    const float* Wv   = (const float*)d_in[8];
    const float* bv   = (const float*)d_in[9];
    const float* Wo   = (const float*)d_in[10];
    const float* bo   = (const float*)d_in[11];

    const size_t T4M = (size_t)BB * SS * D_MODEL;  // 4,194,304 elems
    u16* qh = (u16*)d_ws;                          // [B][NH][S][DH] bf16 (Q pre-scaled)
    u16* kh = qh + T4M;
    u16* vh = kh + T4M;
    u16* ao = vh + T4M;                            // [B][S][D] bf16
    u16* cW = ao + T4M;                            // 4 x 1M bf16 (Wq,Wk,Wv,Wo)
    u16* qb = cW + 4 * (size_t)D_MODEL * D_MODEL;  // q,k,v as bf16 (3 x 4M)
    unsigned long long* pm = (unsigned long long*)(qb + 3 * T4M);
    float* out = (float*)d_out;

    cvtw_kernel<<<dim3(512, 4), 256, 0, stream>>>(Wq, Wk, Wv, Wo, cW);
    cvtin_kernel<<<dim3(2048, 3), 256, 0, stream>>>(q, k, v, qb);
    maskpack_kernel<<<1024, 256, 0, stream>>>(mask, pm);
    qkv_kernel<<<dim3(32, 8, 3), 256, 0, stream>>>(qb, cW, bq, bk, bv, qh, kh, vh);
    attn_kernel<<<dim3(32, NH, BB), 256, 0, stream>>>(qh, kh, vh, pm, ao);
    oproj_kernel<<<dim3(32, 8), 256, 0, stream>>>(ao, cW + 3 * (size_t)D_MODEL * D_MODEL, bo, out);
}